// Round 8
// baseline (173.435 us; speedup 1.0000x reference)
//
#include <hip/hip_runtime.h>

#define B_  4
#define C_  16
#define H_  256
#define W_  256
#define CO_ 16
#define KS_ 3
#define KK_ 9
#define HW_ (H_ * W_)
// ws layout: [0, 8MB) bf16 NHWC image (as u32 words), then fp32 t_ker
#define IMG_WORDS ((size_t)B_ * HW_ * 8)        // 2,097,152 u32 words
#define KER_OFF   IMG_WORDS                     // float offset of t_ker

#define LOBF(u) __uint_as_float((u) << 16)
#define HIBF(u) __uint_as_float((u) & 0xffff0000u)

__device__ __forceinline__ unsigned rne_bf16(float v) {
    unsigned b = __float_as_uint(v);
    return (b + 0x7fffu + ((b >> 16) & 1u)) >> 16;
}

// ------- Kernel 1: NCHW fp32 -> NHWC bf16 pack + ker transpose -------------
__global__ __launch_bounds__(256) void pack_nhwc_bf16(
    const float* __restrict__ inp, const float* __restrict__ ker,
    float* __restrict__ wsp)
{
    unsigned* wsu = (unsigned*)wsp;
    const int t = threadIdx.x;
    const int e = blockIdx.x * 256 + t;     // flat pixel (b*HW + hw)
    const int b = e >> 16;
    const int hw = e & (HW_ - 1);
    const float* src = inp + (size_t)b * (C_ * HW_) + hw;
    float v[C_];
#pragma unroll
    for (int c = 0; c < C_; c++)
        v[c] = src[c * HW_];                // coalesced per c-plane
    unsigned u[8];
#pragma unroll
    for (int j = 0; j < 8; j++)
        u[j] = rne_bf16(v[2 * j]) | (rne_bf16(v[2 * j + 1]) << 16);
    uint4* dst = ((uint4*)wsu) + (size_t)e * 2;   // 32 B per pixel
    dst[0] = make_uint4(u[0], u[1], u[2], u[3]);
    dst[1] = make_uint4(u[4], u[5], u[6], u[7]);

    if (blockIdx.x == 0) {
        // t_ker[kk*256 + c*16 + o] = ker[(o*16+c)*9 + kk]
        for (int i = t; i < KK_ * C_ * CO_; i += 256) {
            const int kk = i >> 8;
            const int c  = (i >> 4) & 15;
            const int o  = i & 15;
            wsp[KER_OFF + i] = ker[(o * C_ + c) * KK_ + kk];
        }
    }
}

// ------- tap address/weight setup ------------------------------------------
__device__ __forceinline__ void tap_setup(
    int h, int w, int kk, float dy, float dx,
    int* idx, float* wt)
{
    const float y = dy + (float)(h - 1 + kk / KS_);
    const float x = dx + (float)(w - 1 + kk % KS_);
    const float y0f = floorf(y);
    const float x0f = floorf(x);
    const int   y0  = (int)y0f;
    const int   x0  = (int)x0f;
    const float wy  = y - y0f;
    const float wx  = x - x0f;

    float w00 = (1.f - wy) * (1.f - wx);
    float w01 = (1.f - wy) * wx;
    float w10 = wy * (1.f - wx);
    float w11 = wy * wx;

    const bool v0y = ((unsigned)y0       < (unsigned)H_);
    const bool v1y = ((unsigned)(y0 + 1) < (unsigned)H_);
    const bool v0x = ((unsigned)x0       < (unsigned)W_);
    const bool v1x = ((unsigned)(x0 + 1) < (unsigned)W_);

    wt[0] = (v0y & v0x) ? w00 : 0.f;
    wt[1] = (v0y & v1x) ? w01 : 0.f;
    wt[2] = (v1y & v0x) ? w10 : 0.f;
    wt[3] = (v1y & v1x) ? w11 : 0.f;

    const int y0c = min(max(y0,     0), H_ - 1);
    const int y1c = min(max(y0 + 1, 0), H_ - 1);
    const int x0c = min(max(x0,     0), W_ - 1);
    const int x1c = min(max(x0 + 1, 0), W_ - 1);

    idx[0] = y0c * W_ + x0c;
    idx[1] = y0c * W_ + x1c;
    idx[2] = y1c * W_ + x0c;
    idx[3] = y1c * W_ + x1c;
}

__device__ __forceinline__ void blend2(
    unsigned a, unsigned b, unsigned c, unsigned d,
    float w0, float w1, float w2, float w3, float* s)
{
    s[0] = w0 * LOBF(a) + w1 * LOBF(b) + w2 * LOBF(c) + w3 * LOBF(d);
    s[1] = w0 * HIBF(a) + w1 * HIBF(b) + w2 * HIBF(c) + w3 * HIBF(d);
}

// ------- Kernel 2: deform-conv + MSE, bf16 NHWC, depth-2 offset pipeline ---
__global__ __launch_bounds__(256, 4) void deform_loss_bf16(
    const float* __restrict__ off, const float* __restrict__ wsp,
    const float* __restrict__ tgt, float* __restrict__ out)
{
    // XCD swizzle: bijection on [0,1024); xcd = blk&7 gets 128 contiguous
    // rows of one image -> per-XCD L2 locality (round-4 verified: 26 MB fetch)
    const int bh = (blockIdx.x & 7) * 128 + (blockIdx.x >> 3);
    const int b  = bh >> 8;
    const int h  = bh & (H_ - 1);
    const int w  = threadIdx.x;
    const int hw = h * W_ + w;

    const float* offb = off + (size_t)b * (2 * KK_ * HW_) + hw;
    const uint4* ib   = ((const uint4*)wsp) + (size_t)b * HW_ * 2;
    const float* tker = wsp + KER_OFF;
    const float* tb   = tgt + (size_t)b * (CO_ * HW_) + hw;

    float acc[CO_];
#pragma unroll
    for (int o = 0; o < CO_; o++) acc[o] = 0.f;

    int   idx[4];
    float wt[4];
    uint4 A0, A1, B0, B1, Cc0, Cc1, D0, D1;   // current tap's corners (bf16)
    float tv[CO_];                            // target values (prefetched)

    // Depth-2 offset pipeline registers:
    //   dyC/dxC = offsets for tap kk+1 (loaded one full iteration ago)
    //   at iteration start we issue the load for tap kk+2
    float dyC, dxC;

    // prologue: offsets for taps 0 and 1, gathers for tap 0
    {
        const float dy0 = offb[0];
        const float dx0 = offb[HW_];
        dyC = offb[2 * HW_];
        dxC = offb[3 * HW_];
        tap_setup(h, w, 0, dy0, dx0, idx, wt);
        A0 = ib[idx[0] * 2]; A1 = ib[idx[0] * 2 + 1];
        B0 = ib[idx[1] * 2]; B1 = ib[idx[1] * 2 + 1];
        Cc0 = ib[idx[2] * 2]; Cc1 = ib[idx[2] * 2 + 1];
        D0 = ib[idx[3] * 2]; D1 = ib[idx[3] * 2 + 1];
    }

#pragma unroll 1
    for (int kk = 0; kk < KK_; kk++) {
        // issue offsets for tap kk+2 NOW; consumed next iteration (~full
        // iteration of shadow ≈ 900+ cyc — covers L3/HBM latency)
        float dyN2 = 0.f, dxN2 = 0.f;
        if (kk + 2 < KK_) {
            dyN2 = offb[(2 * kk + 4) * HW_];
            dxN2 = offb[(2 * kk + 5) * HW_];
        }
        // prefetch target during the last tap's compute (one-time L3 read)
        if (kk == KK_ - 1) {
#pragma unroll
            for (int o = 0; o < CO_; o++) tv[o] = tb[o * HW_];
        }

        // consume: unpack bf16 + bilinear blend -> sc[16]
        float sc[C_];
        blend2(A0.x, B0.x, Cc0.x, D0.x, wt[0], wt[1], wt[2], wt[3], sc + 0);
        blend2(A0.y, B0.y, Cc0.y, D0.y, wt[0], wt[1], wt[2], wt[3], sc + 2);
        blend2(A0.z, B0.z, Cc0.z, D0.z, wt[0], wt[1], wt[2], wt[3], sc + 4);
        blend2(A0.w, B0.w, Cc0.w, D0.w, wt[0], wt[1], wt[2], wt[3], sc + 6);
        blend2(A1.x, B1.x, Cc1.x, D1.x, wt[0], wt[1], wt[2], wt[3], sc + 8);
        blend2(A1.y, B1.y, Cc1.y, D1.y, wt[0], wt[1], wt[2], wt[3], sc + 10);
        blend2(A1.z, B1.z, Cc1.z, D1.z, wt[0], wt[1], wt[2], wt[3], sc + 12);
        blend2(A1.w, B1.w, Cc1.w, D1.w, wt[0], wt[1], wt[2], wt[3], sc + 14);

        // prefetch tap kk+1's gathers using offsets loaded LAST iteration
        if (kk + 1 < KK_) {
            tap_setup(h, w, kk + 1, dyC, dxC, idx, wt);
            A0 = ib[idx[0] * 2]; A1 = ib[idx[0] * 2 + 1];
            B0 = ib[idx[1] * 2]; B1 = ib[idx[1] * 2 + 1];
            Cc0 = ib[idx[2] * 2]; Cc1 = ib[idx[2] * 2 + 1];
            D0 = ib[idx[3] * 2]; D1 = ib[idx[3] * 2 + 1];
        }
        dyC = dyN2; dxC = dxN2;

        // accumulate: kt is wave-uniform -> s_load broadcasts, FMA w/ SGPR
        const float* kt = tker + kk * (C_ * CO_);
#pragma unroll
        for (int c = 0; c < C_; c++) {
            const float s = sc[c];
#pragma unroll
            for (int o = 0; o < CO_; o++)
                acc[o] = fmaf(s, kt[c * 16 + o], acc[o]);
        }
    }

    float part = 0.f;
#pragma unroll
    for (int o = 0; o < CO_; o++) {
        const float d = acc[o] - tv[o];
        part = fmaf(d, d, part);
    }
    part *= (1.0f / (float)((size_t)B_ * CO_ * HW_));

#pragma unroll
    for (int sft = 32; sft > 0; sft >>= 1)
        part += __shfl_down(part, sft, 64);
    if ((threadIdx.x & 63) == 0)
        atomicAdd(out, part);
}

// ------- Fallback (round-1 NCHW kernel, used if ws too small) --------------
__global__ __launch_bounds__(256) void deform_loss_kernel(
    const float* __restrict__ off, const float* __restrict__ inp,
    const float* __restrict__ ker, const float* __restrict__ tgt,
    float* __restrict__ out)
{
    const int idx = blockIdx.x * blockDim.x + threadIdx.x;
    float part = 0.f;
    if (idx < B_ * H_ * W_) {
        const int w  = idx & (W_ - 1);
        const int h  = (idx >> 8) & (H_ - 1);
        const int b  = idx >> 16;
        const int hw = h * W_ + w;
        const float* offb = off + (size_t)b * (2 * KK_ * HW_);
        const float* inpb = inp + (size_t)b * (C_ * HW_);
        float acc[CO_];
#pragma unroll
        for (int o = 0; o < CO_; o++) acc[o] = 0.f;
        for (int kk = 0; kk < KK_; kk++) {
            const float dy = offb[(2 * kk)     * HW_ + hw];
            const float dx = offb[(2 * kk + 1) * HW_ + hw];
            const float y = dy + (float)(h - 1 + kk / KS_);
            const float x = dx + (float)(w - 1 + kk % KS_);
            const float y0f = floorf(y);
            const float x0f = floorf(x);
            const int   y0  = (int)y0f;
            const int   x0  = (int)x0f;
            const float wy  = y - y0f;
            const float wx  = x - x0f;
            float w00 = (1.f - wy) * (1.f - wx);
            float w01 = (1.f - wy) * wx;
            float w10 = wy * (1.f - wx);
            float w11 = wy * wx;
            const bool v0y = ((unsigned)y0       < (unsigned)H_);
            const bool v1y = ((unsigned)(y0 + 1) < (unsigned)H_);
            const bool v0x = ((unsigned)x0       < (unsigned)W_);
            const bool v1x = ((unsigned)(x0 + 1) < (unsigned)W_);
            w00 = (v0y & v0x) ? w00 : 0.f;
            w01 = (v0y & v1x) ? w01 : 0.f;
            w10 = (v1y & v0x) ? w10 : 0.f;
            w11 = (v1y & v1x) ? w11 : 0.f;
            const int i00 = min(max(y0,0),H_-1)*W_ + min(max(x0,0),W_-1);
            const int i01 = min(max(y0,0),H_-1)*W_ + min(max(x0+1,0),W_-1);
            const int i10 = min(max(y0+1,0),H_-1)*W_ + min(max(x0,0),W_-1);
            const int i11 = min(max(y0+1,0),H_-1)*W_ + min(max(x0+1,0),W_-1);
            for (int c = 0; c < C_; c++) {
                const float* pp = inpb + c * HW_;
                const float s = pp[i00]*w00 + pp[i01]*w01 + pp[i10]*w10 + pp[i11]*w11;
#pragma unroll
                for (int o = 0; o < CO_; o++)
                    acc[o] = fmaf(s, ker[(o * C_ + c) * KK_ + kk], acc[o]);
            }
        }
        const float* tb = tgt + (size_t)b * (CO_ * HW_);
#pragma unroll
        for (int o = 0; o < CO_; o++) {
            const float d = acc[o] - tb[o * HW_ + hw];
            part = fmaf(d, d, part);
        }
        part *= (1.0f / (float)((size_t)B_ * CO_ * HW_));
    }
#pragma unroll
    for (int sft = 32; sft > 0; sft >>= 1)
        part += __shfl_down(part, sft, 64);
    if ((threadIdx.x & 63) == 0)
        atomicAdd(out, part);
}

extern "C" void kernel_launch(void* const* d_in, const int* in_sizes, int n_in,
                              void* d_out, int out_size, void* d_ws, size_t ws_size,
                              hipStream_t stream) {
    const float* offsets = (const float*)d_in[0];
    const float* input   = (const float*)d_in[1];
    const float* ker     = (const float*)d_in[2];
    const float* target  = (const float*)d_in[3];
    float* out = (float*)d_out;

    hipMemsetAsync(out, 0, sizeof(float), stream);

    const size_t need = (KER_OFF + (size_t)KK_ * C_ * CO_) * sizeof(float);
    if (ws_size >= need) {
        float* wsp = (float*)d_ws;
        pack_nhwc_bf16<<<(B_ * HW_) / 256, 256, 0, stream>>>(input, ker, wsp);
        deform_loss_bf16<<<B_ * H_, 256, 0, stream>>>(offsets, wsp, target, out);
    } else {
        const int total = B_ * H_ * W_;
        deform_loss_kernel<<<(total + 255) / 256, 256, 0, stream>>>(
            offsets, input, ker, target, out);
    }
}

// Round 9
// 165.414 us; speedup vs baseline: 1.0485x; 1.0485x over previous
//
#include <hip/hip_runtime.h>

#define B_  4
#define C_  16
#define H_  256
#define W_  256
#define CO_ 16
#define KS_ 3
#define KK_ 9
#define HW_ (H_ * W_)
// ws layout: [0, 8MB) bf16 NHWC image (as u32 words), then fp32 t_ker
#define IMG_WORDS ((size_t)B_ * HW_ * 8)        // 2,097,152 u32 words
#define KER_OFF   IMG_WORDS                     // float offset of t_ker

#define LOBF(u) __uint_as_float((u) << 16)
#define HIBF(u) __uint_as_float((u) & 0xffff0000u)

__device__ __forceinline__ unsigned rne_bf16(float v) {
    unsigned b = __float_as_uint(v);
    return (b + 0x7fffu + ((b >> 16) & 1u)) >> 16;
}

// ------- Kernel 1: NCHW fp32 -> NHWC bf16 pack + ker transpose -------------
__global__ __launch_bounds__(256) void pack_nhwc_bf16(
    const float* __restrict__ inp, const float* __restrict__ ker,
    float* __restrict__ wsp)
{
    unsigned* wsu = (unsigned*)wsp;
    const int t = threadIdx.x;
    const int e = blockIdx.x * 256 + t;     // flat pixel (b*HW + hw)
    const int b = e >> 16;
    const int hw = e & (HW_ - 1);
    const float* src = inp + (size_t)b * (C_ * HW_) + hw;
    float v[C_];
#pragma unroll
    for (int c = 0; c < C_; c++)
        v[c] = src[c * HW_];                // coalesced per c-plane
    unsigned u[8];
#pragma unroll
    for (int j = 0; j < 8; j++)
        u[j] = rne_bf16(v[2 * j]) | (rne_bf16(v[2 * j + 1]) << 16);
    uint4* dst = ((uint4*)wsu) + (size_t)e * 2;   // 32 B per pixel
    dst[0] = make_uint4(u[0], u[1], u[2], u[3]);
    dst[1] = make_uint4(u[4], u[5], u[6], u[7]);

    if (blockIdx.x == 0) {
        // t_ker[kk*256 + c*16 + o] = ker[(o*16+c)*9 + kk]
        for (int i = t; i < KK_ * C_ * CO_; i += 256) {
            const int kk = i >> 8;
            const int c  = (i >> 4) & 15;
            const int o  = i & 15;
            wsp[KER_OFF + i] = ker[(o * C_ + c) * KK_ + kk];
        }
    }
}

// ------- tap address/weight setup (pure VALU once offsets are in regs) -----
__device__ __forceinline__ void tap_setup(
    int h, int w, int kk, float dy, float dx,
    int* idx, float* wt)
{
    const float y = dy + (float)(h - 1 + kk / KS_);
    const float x = dx + (float)(w - 1 + kk % KS_);
    const float y0f = floorf(y);
    const float x0f = floorf(x);
    const int   y0  = (int)y0f;
    const int   x0  = (int)x0f;
    const float wy  = y - y0f;
    const float wx  = x - x0f;

    float w00 = (1.f - wy) * (1.f - wx);
    float w01 = (1.f - wy) * wx;
    float w10 = wy * (1.f - wx);
    float w11 = wy * wx;

    const bool v0y = ((unsigned)y0       < (unsigned)H_);
    const bool v1y = ((unsigned)(y0 + 1) < (unsigned)H_);
    const bool v0x = ((unsigned)x0       < (unsigned)W_);
    const bool v1x = ((unsigned)(x0 + 1) < (unsigned)W_);

    wt[0] = (v0y & v0x) ? w00 : 0.f;
    wt[1] = (v0y & v1x) ? w01 : 0.f;
    wt[2] = (v1y & v0x) ? w10 : 0.f;
    wt[3] = (v1y & v1x) ? w11 : 0.f;

    const int y0c = min(max(y0,     0), H_ - 1);
    const int y1c = min(max(y0 + 1, 0), H_ - 1);
    const int x0c = min(max(x0,     0), W_ - 1);
    const int x1c = min(max(x0 + 1, 0), W_ - 1);

    idx[0] = y0c * W_ + x0c;
    idx[1] = y0c * W_ + x1c;
    idx[2] = y1c * W_ + x0c;
    idx[3] = y1c * W_ + x1c;
}

__device__ __forceinline__ void load8(
    uint4* cor, const uint4* __restrict__ ib, const int* idx)
{
    cor[0] = ib[idx[0] * 2]; cor[1] = ib[idx[0] * 2 + 1];
    cor[2] = ib[idx[1] * 2]; cor[3] = ib[idx[1] * 2 + 1];
    cor[4] = ib[idx[2] * 2]; cor[5] = ib[idx[2] * 2 + 1];
    cor[6] = ib[idx[3] * 2]; cor[7] = ib[idx[3] * 2 + 1];
}

__device__ __forceinline__ void blend2(
    unsigned a, unsigned b, unsigned c, unsigned d,
    float w0, float w1, float w2, float w3, float* s)
{
    s[0] = w0 * LOBF(a) + w1 * LOBF(b) + w2 * LOBF(c) + w3 * LOBF(d);
    s[1] = w0 * HIBF(a) + w1 * HIBF(b) + w2 * HIBF(c) + w3 * HIBF(d);
}

// ------- Kernel 2: deform-conv + MSE, fully unrolled, entry-hoisted loads --
__global__ __launch_bounds__(256) void deform_loss_bf16(
    const float* __restrict__ off, const float* __restrict__ wsp,
    const float* __restrict__ tgt, float* __restrict__ out)
{
    // XCD swizzle: bijection on [0,1024); xcd = blk&7 gets 128 contiguous
    // rows of one image -> per-XCD L2 locality (round-4 verified)
    const int bh = (blockIdx.x & 7) * 128 + (blockIdx.x >> 3);
    const int b  = bh >> 8;
    const int h  = bh & (H_ - 1);
    const int w  = threadIdx.x;
    const int hw = h * W_ + w;

    const float* offb = off + (size_t)b * (2 * KK_ * HW_) + hw;
    const uint4* ib   = ((const uint4*)wsp) + (size_t)b * HW_ * 2;
    const float* tker = wsp + KER_OFF;
    const float* tb   = tgt + (size_t)b * (CO_ * HW_) + hw;

    // ALL 18 offset loads issued at entry — in flight together, one latency
    float dyv[KK_], dxv[KK_];
#pragma unroll
    for (int kk = 0; kk < KK_; kk++) {
        dyv[kk] = offb[(2 * kk)     * HW_];
        dxv[kk] = offb[(2 * kk + 1) * HW_];
    }

    float acc[CO_];
#pragma unroll
    for (int o = 0; o < CO_; o++) acc[o] = 0.f;

    uint4 cor[2][8];
    float wts[2][4];
    float tv[CO_];

    // prologue: tap 0 setup + gathers
    {
        int idx[4];
        tap_setup(h, w, 0, dyv[0], dxv[0], idx, wts[0]);
        load8(cor[0], ib, idx);
    }

#pragma unroll
    for (int kk = 0; kk < KK_; kk++) {
        const int cur = kk & 1, nxt = cur ^ 1;

        // issue next tap's gathers first (setup is pure VALU now);
        // they stay in flight across this tap's blend + 256-FMA block
        if (kk + 1 < KK_) {
            int idx[4];
            tap_setup(h, w, kk + 1, dyv[kk + 1], dxv[kk + 1], idx, wts[nxt]);
            load8(cor[nxt], ib, idx);
        } else {
            // last tap: prefetch target in the same shadow (read-once, L3)
#pragma unroll
            for (int o = 0; o < CO_; o++) tv[o] = tb[o * HW_];
        }

        // consume: unpack bf16 + bilinear blend -> sc[16]
        const uint4* cc = cor[cur];
        const float w0 = wts[cur][0], w1 = wts[cur][1],
                    w2 = wts[cur][2], w3 = wts[cur][3];
        float sc[C_];
        blend2(cc[0].x, cc[2].x, cc[4].x, cc[6].x, w0, w1, w2, w3, sc + 0);
        blend2(cc[0].y, cc[2].y, cc[4].y, cc[6].y, w0, w1, w2, w3, sc + 2);
        blend2(cc[0].z, cc[2].z, cc[4].z, cc[6].z, w0, w1, w2, w3, sc + 4);
        blend2(cc[0].w, cc[2].w, cc[4].w, cc[6].w, w0, w1, w2, w3, sc + 6);
        blend2(cc[1].x, cc[3].x, cc[5].x, cc[7].x, w0, w1, w2, w3, sc + 8);
        blend2(cc[1].y, cc[3].y, cc[5].y, cc[7].y, w0, w1, w2, w3, sc + 10);
        blend2(cc[1].z, cc[3].z, cc[5].z, cc[7].z, w0, w1, w2, w3, sc + 12);
        blend2(cc[1].w, cc[3].w, cc[5].w, cc[7].w, w0, w1, w2, w3, sc + 14);

        // accumulate: kt is wave-uniform -> s_load broadcasts, FMA w/ SGPR
        const float* kt = tker + kk * (C_ * CO_);
#pragma unroll
        for (int c = 0; c < C_; c++) {
            const float s = sc[c];
#pragma unroll
            for (int o = 0; o < CO_; o++)
                acc[o] = fmaf(s, kt[c * 16 + o], acc[o]);
        }
    }

    float part = 0.f;
#pragma unroll
    for (int o = 0; o < CO_; o++) {
        const float d = acc[o] - tv[o];
        part = fmaf(d, d, part);
    }
    part *= (1.0f / (float)((size_t)B_ * CO_ * HW_));

#pragma unroll
    for (int sft = 32; sft > 0; sft >>= 1)
        part += __shfl_down(part, sft, 64);
    if ((threadIdx.x & 63) == 0)
        atomicAdd(out, part);
}

// ------- Fallback (round-1 NCHW kernel, used if ws too small) --------------
__global__ __launch_bounds__(256) void deform_loss_kernel(
    const float* __restrict__ off, const float* __restrict__ inp,
    const float* __restrict__ ker, const float* __restrict__ tgt,
    float* __restrict__ out)
{
    const int idx = blockIdx.x * blockDim.x + threadIdx.x;
    float part = 0.f;
    if (idx < B_ * H_ * W_) {
        const int w  = idx & (W_ - 1);
        const int h  = (idx >> 8) & (H_ - 1);
        const int b  = idx >> 16;
        const int hw = h * W_ + w;
        const float* offb = off + (size_t)b * (2 * KK_ * HW_);
        const float* inpb = inp + (size_t)b * (C_ * HW_);
        float acc[CO_];
#pragma unroll
        for (int o = 0; o < CO_; o++) acc[o] = 0.f;
        for (int kk = 0; kk < KK_; kk++) {
            const float dy = offb[(2 * kk)     * HW_ + hw];
            const float dx = offb[(2 * kk + 1) * HW_ + hw];
            const float y = dy + (float)(h - 1 + kk / KS_);
            const float x = dx + (float)(w - 1 + kk % KS_);
            const float y0f = floorf(y);
            const float x0f = floorf(x);
            const int   y0  = (int)y0f;
            const int   x0  = (int)x0f;
            const float wy  = y - y0f;
            const float wx  = x - x0f;
            float w00 = (1.f - wy) * (1.f - wx);
            float w01 = (1.f - wy) * wx;
            float w10 = wy * (1.f - wx);
            float w11 = wy * wx;
            const bool v0y = ((unsigned)y0       < (unsigned)H_);
            const bool v1y = ((unsigned)(y0 + 1) < (unsigned)H_);
            const bool v0x = ((unsigned)x0       < (unsigned)W_);
            const bool v1x = ((unsigned)(x0 + 1) < (unsigned)W_);
            w00 = (v0y & v0x) ? w00 : 0.f;
            w01 = (v0y & v1x) ? w01 : 0.f;
            w10 = (v1y & v0x) ? w10 : 0.f;
            w11 = (v1y & v1x) ? w11 : 0.f;
            const int i00 = min(max(y0,0),H_-1)*W_ + min(max(x0,0),W_-1);
            const int i01 = min(max(y0,0),H_-1)*W_ + min(max(x0+1,0),W_-1);
            const int i10 = min(max(y0+1,0),H_-1)*W_ + min(max(x0,0),W_-1);
            const int i11 = min(max(y0+1,0),H_-1)*W_ + min(max(x0+1,0),W_-1);
            for (int c = 0; c < C_; c++) {
                const float* pp = inpb + c * HW_;
                const float s = pp[i00]*w00 + pp[i01]*w01 + pp[i10]*w10 + pp[i11]*w11;
#pragma unroll
                for (int o = 0; o < CO_; o++)
                    acc[o] = fmaf(s, ker[(o * C_ + c) * KK_ + kk], acc[o]);
            }
        }
        const float* tb = tgt + (size_t)b * (CO_ * HW_);
#pragma unroll
        for (int o = 0; o < CO_; o++) {
            const float d = acc[o] - tb[o * HW_ + hw];
            part = fmaf(d, d, part);
        }
        part *= (1.0f / (float)((size_t)B_ * CO_ * HW_));
    }
#pragma unroll
    for (int sft = 32; sft > 0; sft >>= 1)
        part += __shfl_down(part, sft, 64);
    if ((threadIdx.x & 63) == 0)
        atomicAdd(out, part);
}

extern "C" void kernel_launch(void* const* d_in, const int* in_sizes, int n_in,
                              void* d_out, int out_size, void* d_ws, size_t ws_size,
                              hipStream_t stream) {
    const float* offsets = (const float*)d_in[0];
    const float* input   = (const float*)d_in[1];
    const float* ker     = (const float*)d_in[2];
    const float* target  = (const float*)d_in[3];
    float* out = (float*)d_out;

    hipMemsetAsync(out, 0, sizeof(float), stream);

    const size_t need = (KER_OFF + (size_t)KK_ * C_ * CO_) * sizeof(float);
    if (ws_size >= need) {
        float* wsp = (float*)d_ws;
        pack_nhwc_bf16<<<(B_ * HW_) / 256, 256, 0, stream>>>(input, ker, wsp);
        deform_loss_bf16<<<B_ * H_, 256, 0, stream>>>(offsets, wsp, target, out);
    } else {
        const int total = B_ * H_ * W_;
        deform_loss_kernel<<<(total + 255) / 256, 256, 0, stream>>>(
            offsets, input, ker, target, out);
    }
}